// Round 16
// baseline (55.660 us; speedup 1.0000x reference)
//
#include <hip/hip_runtime.h>
#include <hip/hip_bf16.h>
#include <math.h>

#define KN 20
#define DD 64
#define WPB 4

typedef __hip_bfloat16 bf16;
typedef __attribute__((ext_vector_type(8))) short short8;   // 8 bf16 (4 VGPRs)
typedef __attribute__((ext_vector_type(16))) float f32x16;  // MFMA 32x32 acc

__device__ inline ushort f2bf(float f) {                    // fp32 -> bf16 RNE
    unsigned u = __builtin_bit_cast(unsigned, f);
    u += 0x7fffu + ((u >> 16) & 1u);
    return (ushort)(u >> 16);
}

// DPP-based 32-lane sum (VALU pipe, zero DS ops). Valid in lanes 31 and 63.
__device__ inline float dpp_sum32(float x) {
    int v = __builtin_bit_cast(int, x);
    float s = x;
    s += __builtin_bit_cast(float, __builtin_amdgcn_update_dpp(0, v, 0x111, 0xf, 0xf, true)); // row_shr:1
    v = __builtin_bit_cast(int, s);
    s += __builtin_bit_cast(float, __builtin_amdgcn_update_dpp(0, v, 0x112, 0xf, 0xf, true)); // row_shr:2
    v = __builtin_bit_cast(int, s);
    s += __builtin_bit_cast(float, __builtin_amdgcn_update_dpp(0, v, 0x114, 0xf, 0xf, true)); // row_shr:4
    v = __builtin_bit_cast(int, s);
    s += __builtin_bit_cast(float, __builtin_amdgcn_update_dpp(0, v, 0x118, 0xf, 0xf, true)); // row_shr:8
    v = __builtin_bit_cast(int, s);
    s += __builtin_bit_cast(float, __builtin_amdgcn_update_dpp(0, v, 0x142, 0xf, 0xf, true)); // ROW_BCAST15
    return s;   // lane31 = sum(0..31), lane63 = sum(32..63)
}

// ================= single fused kernel ========================================
// R16: precompute phase DELETED (it was ~37us of the 52.6 total; Y-fold was a
// VALU-era optimization, unnecessary on MFMA). Per wave (1 batch element):
//   GEMM1: x = [Su@Eu_g | Si@Ei_g]  (A=scores f2bf [R8-verified], B=emb rows
//          staged bf16 in wave-private LDS [same layout as the old Y staging])
//   GEMM2: h1 = relu(x @ w1 + b1)   (K=128: 8 ksteps x 2 ntiles = 16 MFMA;
//          w1 frags staged once per block in LDS, one barrier after staging)
//   GEMM3: h2 = relu(h1 @ w2 + b2)  (4 MFMA, as R9-verified)
//   layer3 + sigmoid + mean via DPP (R15).
// LDS 44KB/block: per-wave buf (Eg->x->h1 union, in-order DS, wave-private)
// + block-shared w1f (16KB) + w2f (4KB). Grid 4096 = 16384/4 exact, so the
// single __syncthreads is convergent. (256,4): R4/R5 spill lesson.
__global__ __launch_bounds__(256, 4) void cnn_fused(
    const int* __restrict__ user_idxs, const int* __restrict__ item_idxs,
    const int* __restrict__ user_idx_tensor, const float* __restrict__ uscr,
    const int* __restrict__ item_idx_tensor, const float* __restrict__ iscr,
    const float* __restrict__ emb_u, const float* __restrict__ emb_i,
    const float* __restrict__ w1, const float* __restrict__ b1,
    const float* __restrict__ w2, const float* __restrict__ b2,
    const float* __restrict__ w3, const float* __restrict__ b3,
    float* __restrict__ out, int Bn)
{
    __shared__ ushort buf[WPB][3072];   // per-wave: [side][24][64] Eg -> x -> h1
    __shared__ ushort w1f[8192];        // w1 B-frags: [(t*2+g)*64+col][8j]
    __shared__ ushort w2f[2048];        // w2 B-frags: [(t*2+g)*32+col][8j]

    const int w    = threadIdx.x >> 6;
    const int lane = threadIdx.x & 63;
    const int g    = lane >> 5;
    const int c    = lane & 31;

    // ---- stage w1/w2 frag tables cooperatively (L2-hot scalar loads) ----
    {
        const int tid = threadIdx.x;
        #pragma unroll
        for (int s0 = 0; s0 < 4; ++s0) {            // 1024 w1f slots / 256 thr
            const int s  = s0 * 256 + tid;
            const int tg = s >> 6, col = s & 63;    // tg = t*2+gg
            const int t = tg >> 1, gg = tg & 1;
            ushort tmp[8];
            #pragma unroll
            for (int j = 0; j < 8; ++j)
                tmp[j] = f2bf(w1[(16 * t + 8 * gg + j) * DD + col]);
            *(short8*)&w1f[(size_t)s * 8] = *(const short8*)tmp;
        }
        const int t = tid >> 6, gg = (tid >> 5) & 1, o = tid & 31;
        ushort tmp[8];
        #pragma unroll
        for (int j = 0; j < 8; ++j)
            tmp[j] = f2bf(w2[(16 * t + 8 * gg + j) * 32 + o]);
        *(short8*)&w2f[(size_t)tid * 8] = *(const short8*)tmp;
    }
    __syncthreads();

    int b = blockIdx.x * WPB + w;
    if (b >= Bn) b = Bn - 1;               // clamp (grid exact for B=16384)

    const int uid = user_idxs[b];
    const int iid = item_idxs[b];

    int nvu = 0, nvi = 0;
    if (lane < KN) {
        nvu = user_idx_tensor[uid * KN + lane];
        nvi = item_idx_tensor[iid * KN + lane];
    }

    // ---- stage emb rows (both sides) -> bf16 wave-private LDS ----
    #pragma unroll
    for (int side = 0; side < 2; ++side) {
        const float* E = side ? emb_i : emb_u;
        const int nv = side ? nvi : nvu;
        #pragma unroll
        for (int i = 0; i < 3; ++i) {                 // rows 8i..8i+7 (20..23 junk)
            int nr = __shfl(nv, 8 * i + (lane >> 3)); // lanes>=KN hold 0: safe
            const float* er = E + (size_t)nr * DD + (lane & 7) * 8;
            float4 v0 = *(const float4*)er;
            float4 v1 = *(const float4*)(er + 4);
            ushort tmp[8];
            tmp[0] = f2bf(v0.x); tmp[1] = f2bf(v0.y);
            tmp[2] = f2bf(v0.z); tmp[3] = f2bf(v0.w);
            tmp[4] = f2bf(v1.x); tmp[5] = f2bf(v1.y);
            tmp[6] = f2bf(v1.z); tmp[7] = f2bf(v1.w);
            *(short8*)&buf[w][side * 1536 + i * 512 + lane * 8] = *(const short8*)tmp;
        }
    }

    // v_perm selector: pack col c from two row-dwords
    const uint selp = 0x05040100u | ((c & 1) ? 0x02020202u : 0x0u);
    const int  cb   = c & ~1;

    // ---- GEMM1 per side: scored = S @ Eg ; write x half into same region ----
    #pragma unroll
    for (int side = 0; side < 2; ++side) {
        const int nv = side ? nvi : nvu;
        const int n_r = __shfl(nv, c);

        // A frags: score row n_r (fp32 -> bf16, R8-verified path)
        const float* arow = (side ? iscr : uscr) + (size_t)n_r * KN;
        float4 a0 = *(const float4*)(arow + 8 * g);
        float4 a1 = *(const float4*)(arow + 8 * g + 4);
        short8 A0, A1 = {};
        A0[0] = (short)f2bf(a0.x); A0[1] = (short)f2bf(a0.y);
        A0[2] = (short)f2bf(a0.z); A0[3] = (short)f2bf(a0.w);
        A0[4] = (short)f2bf(a1.x); A0[5] = (short)f2bf(a1.y);
        A0[6] = (short)f2bf(a1.z); A0[7] = (short)f2bf(a1.w);
        float4 a2 = *(const float4*)(arow + 16);
        A1[0] = (short)f2bf(a2.x); A1[1] = (short)f2bf(a2.y);
        A1[2] = (short)f2bf(a2.z); A1[3] = (short)f2bf(a2.w);

        // B frags from staged Eg (dword reads -> ds_read2 merges + v_perm)
        const int sb0u = side * 1536;
        uint r0[8], r1[8];
        #pragma unroll
        for (int j = 0; j < 8; ++j) {
            r0[j] = *(const uint*)&buf[w][sb0u + (8 * g + j) * DD + cb];
            r1[j] = *(const uint*)&buf[w][sb0u + (8 * g + j) * DD + 32 + cb];
        }
        uint4 pk0, pk1;
        pk0.x = __builtin_amdgcn_perm(r0[1], r0[0], selp);
        pk0.y = __builtin_amdgcn_perm(r0[3], r0[2], selp);
        pk0.z = __builtin_amdgcn_perm(r0[5], r0[4], selp);
        pk0.w = __builtin_amdgcn_perm(r0[7], r0[6], selp);
        pk1.x = __builtin_amdgcn_perm(r1[1], r1[0], selp);
        pk1.y = __builtin_amdgcn_perm(r1[3], r1[2], selp);
        pk1.z = __builtin_amdgcn_perm(r1[5], r1[4], selp);
        pk1.w = __builtin_amdgcn_perm(r1[7], r1[6], selp);
        f32x16 za0 = {}, za1 = {};
        za0 = __builtin_amdgcn_mfma_f32_32x32x16_bf16(A0, __builtin_bit_cast(short8, pk0), za0, 0, 0, 0);
        za1 = __builtin_amdgcn_mfma_f32_32x32x16_bf16(A0, __builtin_bit_cast(short8, pk1), za1, 0, 0, 0);

        uint q0[4], q1[4];
        #pragma unroll
        for (int j = 0; j < 4; ++j) {
            q0[j] = *(const uint*)&buf[w][sb0u + (16 + j) * DD + cb];
            q1[j] = *(const uint*)&buf[w][sb0u + (16 + j) * DD + 32 + cb];
        }
        uint4 pk2 = {}, pk3 = {};
        if (g == 0) {
            pk2.x = __builtin_amdgcn_perm(q0[1], q0[0], selp);
            pk2.y = __builtin_amdgcn_perm(q0[3], q0[2], selp);
            pk3.x = __builtin_amdgcn_perm(q1[1], q1[0], selp);
            pk3.y = __builtin_amdgcn_perm(q1[3], q1[2], selp);
        }
        za0 = __builtin_amdgcn_mfma_f32_32x32x16_bf16(A1, __builtin_bit_cast(short8, pk2), za0, 0, 0, 0);
        za1 = __builtin_amdgcn_mfma_f32_32x32x16_bf16(A1, __builtin_bit_cast(short8, pk3), za1, 0, 0, 0);

        // x half -> bf16 swizzled LDS over this side's Eg region (no bias/relu)
        #pragma unroll
        for (int r = 0; r < 12; ++r) {
            const int row = (r & 3) + 8 * (r >> 2) + 4 * g;
            if (row < KN) {
                const int ch0 = (c >> 3) ^ (row & 7);
                const int ch1 = (4 + (c >> 3)) ^ (row & 7);
                buf[w][side * 1536 + row * DD + ch0 * 8 + (c & 7)] = f2bf(za0[r]);
                buf[w][side * 1536 + row * DD + ch1 * 8 + (c & 7)] = f2bf(za1[r]);
            }
        }
    }

    // ---- GEMM2: h1(20x64) = x(20x128) @ w1(128x64), 8 ksteps x 2 ntiles ----
    const int ar = (c < KN) ? c : 0;
    f32x16 h0 = {}, h1a = {};
    #pragma unroll
    for (int t = 0; t < 8; ++t) {
        const int half = t >> 2, tq = t & 3;
        const int chunk = (2 * tq + g) ^ (ar & 7);
        short8 A = *(const short8*)&buf[w][half * 1536 + ar * DD + chunk * 8];
        short8 B0 = *(const short8*)&w1f[(size_t)((t * 2 + g) * DD + c) * 8];
        short8 B1 = *(const short8*)&w1f[(size_t)((t * 2 + g) * DD + 32 + c) * 8];
        h0  = __builtin_amdgcn_mfma_f32_32x32x16_bf16(A, B0, h0, 0, 0, 0);
        h1a = __builtin_amdgcn_mfma_f32_32x32x16_bf16(A, B1, h1a, 0, 0, 0);
    }

    // ---- bias + relu -> bf16 swizzled h1 into region [0..1536) ----
    const float b1v0 = b1[c];
    const float b1v1 = b1[32 + c];
    #pragma unroll
    for (int r = 0; r < 12; ++r) {
        const int row = (r & 3) + 8 * (r >> 2) + 4 * g;
        if (row < KN) {
            const int ch0 = (c >> 3) ^ (row & 7);
            const int ch1 = (4 + (c >> 3)) ^ (row & 7);
            buf[w][row * DD + ch0 * 8 + (c & 7)] = f2bf(fmaxf(h0[r] + b1v0, 0.f));
            buf[w][row * DD + ch1 * 8 + (c & 7)] = f2bf(fmaxf(h1a[r] + b1v1, 0.f));
        }
    }

    // ---- GEMM3: h2(20x32) = h1(20x64) @ w2(64x32), 4 ksteps ----
    f32x16 c2 = {};
    #pragma unroll
    for (int t = 0; t < 4; ++t) {
        const int chunk = (2 * t + g) ^ (ar & 7);
        short8 A = *(const short8*)&buf[w][ar * DD + chunk * 8];
        short8 B = *(const short8*)&w2f[(size_t)((t * 2 + g) * 32 + c) * 8];
        c2 = __builtin_amdgcn_mfma_f32_32x32x16_bf16(A, B, c2, 0, 0, 0);
    }

    // ---- layer3: bias+relu, *w3, DPP-sum over 32 cols, sigmoid, mean ----
    const float b2v = b2[c];
    const float w3v = w3[c];
    const float b3v = b3[0];
    float sum = 0.f;
    #pragma unroll
    for (int r = 0; r < 12; ++r) {
        float h2v = fmaxf(c2[r] + b2v, 0.f);
        float p = dpp_sum32(h2v * w3v);            // valid in lanes 31 / 63
        float logit = p + b3v;
        if (g == 0 || r < 8)                       // valid rows: g0 12, g1 8 (=20)
            sum += 1.f / (1.f + __expf(-logit));
    }
    sum += __shfl_xor(sum, 32);                    // lane31 += lane63's sum
    if (lane == 31) out[b] = sum * (1.f / KN);
}

extern "C" void kernel_launch(void* const* d_in, const int* in_sizes, int n_in,
                              void* d_out, int out_size, void* d_ws, size_t ws_size,
                              hipStream_t stream) {
    const int*   user_idxs       = (const int*)  d_in[0];
    const int*   item_idxs       = (const int*)  d_in[1];
    const int*   user_idx_tensor = (const int*)  d_in[2];
    const float* user_scr_tensor = (const float*)d_in[3];
    const int*   item_idx_tensor = (const int*)  d_in[4];
    const float* item_scr_tensor = (const float*)d_in[5];
    const float* user_emb        = (const float*)d_in[6];
    const float* item_emb        = (const float*)d_in[7];
    const float* w1 = (const float*)d_in[8];
    const float* b1 = (const float*)d_in[9];
    const float* w2 = (const float*)d_in[10];
    const float* b2 = (const float*)d_in[11];
    const float* w3 = (const float*)d_in[12];
    const float* b3 = (const float*)d_in[13];
    float* out = (float*)d_out;

    const int Bn = in_sizes[0];
    const int grid = (Bn + WPB - 1) / WPB;
    cnn_fused<<<grid, 256, 0, stream>>>(
        user_idxs, item_idxs, user_idx_tensor, user_scr_tensor,
        item_idx_tensor, item_scr_tensor, user_emb, item_emb,
        w1, b1, w2, b2, w3, b3, out, Bn);
}

// Round 18
// 52.989 us; speedup vs baseline: 1.0504x; 1.0504x over previous
//
#include <hip/hip_runtime.h>
#include <hip/hip_bf16.h>
#include <math.h>

#define KN 20
#define DD 64
#define WPB 4

typedef __hip_bfloat16 bf16;
typedef __attribute__((ext_vector_type(8))) short short8;   // 8 bf16 (4 VGPRs)
typedef __attribute__((ext_vector_type(16))) float f32x16;  // MFMA 32x32 acc

// native RNE casts; compiler fuses adjacent pairs into v_cvt_pk_bf16_f32.
// (R16's hand-rolled bit-twiddle was ~4 int-ALU ops per convert, ~700 VALU/thr.)
__device__ inline ushort f2bf(float f) {
    return __builtin_bit_cast(ushort, __float2bfloat16(f));
}
__device__ inline uint pk2bf(float lo, float hi) {   // [15:0]=lo, [31:16]=hi
    return (uint)f2bf(lo) | ((uint)f2bf(hi) << 16);
}

// DPP-based 32-lane sum (VALU pipe, zero DS ops). Valid in lanes 31 and 63.
__device__ inline float dpp_sum32(float x) {
    int v = __builtin_bit_cast(int, x);
    float s = x;
    s += __builtin_bit_cast(float, __builtin_amdgcn_update_dpp(0, v, 0x111, 0xf, 0xf, true)); // row_shr:1
    v = __builtin_bit_cast(int, s);
    s += __builtin_bit_cast(float, __builtin_amdgcn_update_dpp(0, v, 0x112, 0xf, 0xf, true)); // row_shr:2
    v = __builtin_bit_cast(int, s);
    s += __builtin_bit_cast(float, __builtin_amdgcn_update_dpp(0, v, 0x114, 0xf, 0xf, true)); // row_shr:4
    v = __builtin_bit_cast(int, s);
    s += __builtin_bit_cast(float, __builtin_amdgcn_update_dpp(0, v, 0x118, 0xf, 0xf, true)); // row_shr:8
    v = __builtin_bit_cast(int, s);
    s += __builtin_bit_cast(float, __builtin_amdgcn_update_dpp(0, v, 0x142, 0xf, 0xf, true)); // ROW_BCAST15
    return s;   // lane31 = sum(0..31), lane63 = sum(32..63)
}

// ================= single fused kernel (R16 structure) ========================
// R17: (1) native packed bf16 cvt; (2) buf trimmed [24]->[20] rows/side:
// LDS 44->40KB = exactly 4 blocks/CU (was 3). Pad rows were never read
// (kstep1 A1[4..7]=0 covers B rows 20..23).
__global__ __launch_bounds__(256, 4) void cnn_fused(
    const int* __restrict__ user_idxs, const int* __restrict__ item_idxs,
    const int* __restrict__ user_idx_tensor, const float* __restrict__ uscr,
    const int* __restrict__ item_idx_tensor, const float* __restrict__ iscr,
    const float* __restrict__ emb_u, const float* __restrict__ emb_i,
    const float* __restrict__ w1, const float* __restrict__ b1,
    const float* __restrict__ w2, const float* __restrict__ b2,
    const float* __restrict__ w3, const float* __restrict__ b3,
    float* __restrict__ out, int Bn)
{
    __shared__ ushort buf[WPB][2560];   // per-wave: [side][20][64] Eg -> x -> h1
    __shared__ ushort w1f[8192];        // w1 B-frags: [(t*2+g)*64+col][8j]
    __shared__ ushort w2f[2048];        // w2 B-frags: [(t*2+g)*32+col][8j]

    const int w    = threadIdx.x >> 6;
    const int lane = threadIdx.x & 63;
    const int g    = lane >> 5;
    const int c    = lane & 31;

    // ---- stage w1/w2 frag tables cooperatively (packed cvt) ----
    {
        const int tid = threadIdx.x;
        #pragma unroll
        for (int s0 = 0; s0 < 4; ++s0) {            // 1024 w1f slots / 256 thr
            const int s  = s0 * 256 + tid;
            const int tg = s >> 6, col = s & 63;    // tg = t*2+gg
            const int t = tg >> 1, gg = tg & 1;
            const float* src = w1 + (size_t)(16 * t + 8 * gg) * DD + col;
            uint4 q;
            q.x = pk2bf(src[0 * DD], src[1 * DD]);
            q.y = pk2bf(src[2 * DD], src[3 * DD]);
            q.z = pk2bf(src[4 * DD], src[5 * DD]);
            q.w = pk2bf(src[6 * DD], src[7 * DD]);
            *(uint4*)&w1f[(size_t)s * 8] = q;
        }
        const int t = tid >> 6, gg = (tid >> 5) & 1, o = tid & 31;
        const float* src2 = w2 + (size_t)(16 * t + 8 * gg) * 32 + o;
        uint4 q2;
        q2.x = pk2bf(src2[0 * 32], src2[1 * 32]);
        q2.y = pk2bf(src2[2 * 32], src2[3 * 32]);
        q2.z = pk2bf(src2[4 * 32], src2[5 * 32]);
        q2.w = pk2bf(src2[6 * 32], src2[7 * 32]);
        *(uint4*)&w2f[(size_t)tid * 8] = q2;
    }
    __syncthreads();

    int b = blockIdx.x * WPB + w;
    if (b >= Bn) b = Bn - 1;               // clamp (grid exact for B=16384)

    const int uid = user_idxs[b];
    const int iid = item_idxs[b];

    int nvu = 0, nvi = 0;
    if (lane < KN) {
        nvu = user_idx_tensor[uid * KN + lane];
        nvi = item_idx_tensor[iid * KN + lane];
    }

    // ---- stage emb rows (both sides) -> bf16 wave-private LDS (20 rows) ----
    #pragma unroll
    for (int side = 0; side < 2; ++side) {
        const float* E = side ? emb_i : emb_u;
        const int nv = side ? nvi : nvu;
        #pragma unroll
        for (int i = 0; i < 3; ++i) {                 // rows 8i..; i==2: only 16..19
            if (i < 2 || lane < 32) {
                int nr = __shfl(nv, 8 * i + (lane >> 3));
                const float* er = E + (size_t)nr * DD + (lane & 7) * 8;
                float4 v0 = *(const float4*)er;
                float4 v1 = *(const float4*)(er + 4);
                uint4 t4;
                t4.x = pk2bf(v0.x, v0.y);
                t4.y = pk2bf(v0.z, v0.w);
                t4.z = pk2bf(v1.x, v1.y);
                t4.w = pk2bf(v1.z, v1.w);
                *(uint4*)&buf[w][side * 1280 + i * 512 + lane * 8] = t4;
            }
        }
    }

    // v_perm selector: pack col c from two row-dwords
    const uint selp = 0x05040100u | ((c & 1) ? 0x02020202u : 0x0u);
    const int  cb   = c & ~1;

    // ---- GEMM1 per side: scored = S @ Eg ; write x half into same region ----
    #pragma unroll
    for (int side = 0; side < 2; ++side) {
        const int nv = side ? nvi : nvu;
        const int n_r = __shfl(nv, c);

        // A frags: score row n_r (fp32 -> bf16 packed)
        const float* arow = (side ? iscr : uscr) + (size_t)n_r * KN;
        float4 a0 = *(const float4*)(arow + 8 * g);
        float4 a1 = *(const float4*)(arow + 8 * g + 4);
        float4 a2 = *(const float4*)(arow + 16);
        uint4 au;
        au.x = pk2bf(a0.x, a0.y); au.y = pk2bf(a0.z, a0.w);
        au.z = pk2bf(a1.x, a1.y); au.w = pk2bf(a1.z, a1.w);
        short8 A0 = __builtin_bit_cast(short8, au);
        uint4 au1 = {};
        au1.x = pk2bf(a2.x, a2.y); au1.y = pk2bf(a2.z, a2.w);
        short8 A1 = __builtin_bit_cast(short8, au1);

        // B frags from staged Eg (dword reads -> ds_read2 merges + v_perm)
        const int sb0u = side * 1280;
        uint r0[8], r1[8];
        #pragma unroll
        for (int j = 0; j < 8; ++j) {
            r0[j] = *(const uint*)&buf[w][sb0u + (8 * g + j) * DD + cb];
            r1[j] = *(const uint*)&buf[w][sb0u + (8 * g + j) * DD + 32 + cb];
        }
        uint4 pk0, pk1;
        pk0.x = __builtin_amdgcn_perm(r0[1], r0[0], selp);
        pk0.y = __builtin_amdgcn_perm(r0[3], r0[2], selp);
        pk0.z = __builtin_amdgcn_perm(r0[5], r0[4], selp);
        pk0.w = __builtin_amdgcn_perm(r0[7], r0[6], selp);
        pk1.x = __builtin_amdgcn_perm(r1[1], r1[0], selp);
        pk1.y = __builtin_amdgcn_perm(r1[3], r1[2], selp);
        pk1.z = __builtin_amdgcn_perm(r1[5], r1[4], selp);
        pk1.w = __builtin_amdgcn_perm(r1[7], r1[6], selp);
        f32x16 za0 = {}, za1 = {};
        za0 = __builtin_amdgcn_mfma_f32_32x32x16_bf16(A0, __builtin_bit_cast(short8, pk0), za0, 0, 0, 0);
        za1 = __builtin_amdgcn_mfma_f32_32x32x16_bf16(A0, __builtin_bit_cast(short8, pk1), za1, 0, 0, 0);

        uint q0[4], q1[4];
        #pragma unroll
        for (int j = 0; j < 4; ++j) {
            q0[j] = *(const uint*)&buf[w][sb0u + (16 + j) * DD + cb];
            q1[j] = *(const uint*)&buf[w][sb0u + (16 + j) * DD + 32 + cb];
        }
        uint4 pk2 = {}, pk3 = {};
        if (g == 0) {
            pk2.x = __builtin_amdgcn_perm(q0[1], q0[0], selp);
            pk2.y = __builtin_amdgcn_perm(q0[3], q0[2], selp);
            pk3.x = __builtin_amdgcn_perm(q1[1], q1[0], selp);
            pk3.y = __builtin_amdgcn_perm(q1[3], q1[2], selp);
        }
        za0 = __builtin_amdgcn_mfma_f32_32x32x16_bf16(A1, __builtin_bit_cast(short8, pk2), za0, 0, 0, 0);
        za1 = __builtin_amdgcn_mfma_f32_32x32x16_bf16(A1, __builtin_bit_cast(short8, pk3), za1, 0, 0, 0);

        // x half -> bf16 swizzled LDS over this side's Eg region (no bias/relu)
        #pragma unroll
        for (int r = 0; r < 12; ++r) {
            const int row = (r & 3) + 8 * (r >> 2) + 4 * g;
            if (row < KN) {
                const int ch0 = (c >> 3) ^ (row & 7);
                const int ch1 = (4 + (c >> 3)) ^ (row & 7);
                buf[w][side * 1280 + row * DD + ch0 * 8 + (c & 7)] = f2bf(za0[r]);
                buf[w][side * 1280 + row * DD + ch1 * 8 + (c & 7)] = f2bf(za1[r]);
            }
        }
    }

    // ---- GEMM2: h1(20x64) = x(20x128) @ w1(128x64), 8 ksteps x 2 ntiles ----
    const int ar = (c < KN) ? c : 0;
    f32x16 h0 = {}, h1a = {};
    #pragma unroll
    for (int t = 0; t < 8; ++t) {
        const int half = t >> 2, tq = t & 3;
        const int chunk = (2 * tq + g) ^ (ar & 7);
        short8 A = *(const short8*)&buf[w][half * 1280 + ar * DD + chunk * 8];
        short8 B0 = *(const short8*)&w1f[(size_t)((t * 2 + g) * DD + c) * 8];
        short8 B1 = *(const short8*)&w1f[(size_t)((t * 2 + g) * DD + 32 + c) * 8];
        h0  = __builtin_amdgcn_mfma_f32_32x32x16_bf16(A, B0, h0, 0, 0, 0);
        h1a = __builtin_amdgcn_mfma_f32_32x32x16_bf16(A, B1, h1a, 0, 0, 0);
    }

    // ---- bias + relu -> bf16 swizzled h1 into region [0..1280) ----
    const float b1v0 = b1[c];
    const float b1v1 = b1[32 + c];
    #pragma unroll
    for (int r = 0; r < 12; ++r) {
        const int row = (r & 3) + 8 * (r >> 2) + 4 * g;
        if (row < KN) {
            const int ch0 = (c >> 3) ^ (row & 7);
            const int ch1 = (4 + (c >> 3)) ^ (row & 7);
            buf[w][row * DD + ch0 * 8 + (c & 7)] = f2bf(fmaxf(h0[r] + b1v0, 0.f));
            buf[w][row * DD + ch1 * 8 + (c & 7)] = f2bf(fmaxf(h1a[r] + b1v1, 0.f));
        }
    }

    // ---- GEMM3: h2(20x32) = h1(20x64) @ w2(64x32), 4 ksteps ----
    f32x16 c2 = {};
    #pragma unroll
    for (int t = 0; t < 4; ++t) {
        const int chunk = (2 * t + g) ^ (ar & 7);
        short8 A = *(const short8*)&buf[w][ar * DD + chunk * 8];
        short8 B = *(const short8*)&w2f[(size_t)((t * 2 + g) * 32 + c) * 8];
        c2 = __builtin_amdgcn_mfma_f32_32x32x16_bf16(A, B, c2, 0, 0, 0);
    }

    // ---- layer3: bias+relu, *w3, DPP-sum over 32 cols, sigmoid, mean ----
    const float b2v = b2[c];
    const float w3v = w3[c];
    const float b3v = b3[0];
    float sum = 0.f;
    #pragma unroll
    for (int r = 0; r < 12; ++r) {
        float h2v = fmaxf(c2[r] + b2v, 0.f);
        float p = dpp_sum32(h2v * w3v);            // valid in lanes 31 / 63
        float logit = p + b3v;
        if (g == 0 || r < 8)                       // valid rows: g0 12, g1 8 (=20)
            sum += 1.f / (1.f + __expf(-logit));
    }
    sum += __shfl_xor(sum, 32);                    // lane31 += lane63's sum
    if (lane == 31) out[b] = sum * (1.f / KN);
}

extern "C" void kernel_launch(void* const* d_in, const int* in_sizes, int n_in,
                              void* d_out, int out_size, void* d_ws, size_t ws_size,
                              hipStream_t stream) {
    const int*   user_idxs       = (const int*)  d_in[0];
    const int*   item_idxs       = (const int*)  d_in[1];
    const int*   user_idx_tensor = (const int*)  d_in[2];
    const float* user_scr_tensor = (const float*)d_in[3];
    const int*   item_idx_tensor = (const int*)  d_in[4];
    const float* item_scr_tensor = (const float*)d_in[5];
    const float* user_emb        = (const float*)d_in[6];
    const float* item_emb        = (const float*)d_in[7];
    const float* w1 = (const float*)d_in[8];
    const float* b1 = (const float*)d_in[9];
    const float* w2 = (const float*)d_in[10];
    const float* b2 = (const float*)d_in[11];
    const float* w3 = (const float*)d_in[12];
    const float* b3 = (const float*)d_in[13];
    float* out = (float*)d_out;

    const int Bn = in_sizes[0];
    const int grid = (Bn + WPB - 1) / WPB;
    cnn_fused<<<grid, 256, 0, stream>>>(
        user_idxs, item_idxs, user_idx_tensor, user_scr_tensor,
        item_idx_tensor, item_scr_tensor, user_emb, item_emb,
        w1, b1, w2, b2, w3, b3, out, Bn);
}